// Round 1
// baseline (1383.831 us; speedup 1.0000x reference)
//
#include <hip/hip_runtime.h>
#include <hip/hip_bf16.h>
#include <cstdint>
#include <cstddef>

// ---------- types ----------
typedef short bf16x8 __attribute__((ext_vector_type(8)));   // 8 bf16 in 4 VGPRs
typedef float f32x4 __attribute__((ext_vector_type(4)));

#define BM 128
#define BN 128
#define BK 32

// async global->LDS, 16B per lane. LDS dest is wave-uniform base + lane*16.
__device__ __forceinline__ void gl_lds16(const __hip_bfloat16* gp, __hip_bfloat16* lp) {
  __builtin_amdgcn_global_load_lds((const __attribute__((address_space(1))) void*)gp,
                                   (__attribute__((address_space(3))) void*)lp, 16, 0, 0);
}

// ---------- weight transpose + bf16 convert: dst[c*R + r] = src[r*C + c] ----------
__global__ void __launch_bounds__(256) wtrans_kernel(const float* __restrict__ src,
                                                     __hip_bfloat16* __restrict__ dst,
                                                     int R, int C) {
  int idx = blockIdx.x * 256 + threadIdx.x;
  if (idx >= R * C) return;
  int r = idx / C, c = idx % C;
  dst[(size_t)c * R + r] = __float2bfloat16(src[idx]);
}

// ---------- per-row bitonic sort of 512 f32; emits h0[b][0..512)=x, h0[b][512..1024)=sorted ----------
__global__ void __launch_bounds__(256) sort_kernel(const float* __restrict__ x,
                                                   __hip_bfloat16* __restrict__ h0) {
  __shared__ float s[512];
  int b = blockIdx.x, t = threadIdx.x;
  const float* xr = x + (size_t)b * 512;
  __hip_bfloat16* h = h0 + (size_t)b * 1024;
  float v0 = xr[t], v1 = xr[t + 256];
  s[t] = v0; s[t + 256] = v1;
  h[t] = __float2bfloat16(v0);
  h[t + 256] = __float2bfloat16(v1);
  __syncthreads();
  for (int k = 2; k <= 512; k <<= 1) {
    for (int j = k >> 1; j > 0; j >>= 1) {
      int i = ((t & ~(j - 1)) << 1) | (t & (j - 1));  // insert 0 bit at position log2(j)
      int ixj = i | j;
      float a = s[i], c = s[ixj];
      bool up = ((i & k) == 0);
      if ((a > c) == up) { s[i] = c; s[ixj] = a; }
      __syncthreads();
    }
  }
  h[512 + t] = __float2bfloat16(s[t]);
  h[512 + t + 256] = __float2bfloat16(s[t + 256]);
}

// ---------- GEMM: C(M,N) = A(M,K) @ BT(N,K)^T, bf16 in, f32 accum ----------
// EPI: 1 = perm-scatter after GEMM1 (rows=2b+p, N=512)
//      2 = perm-scatter after G2   (rows=4b+g, N=256)
//      3 = relu, plain bf16 store
//      4 = sigmoid(acc) * x, f32 store
template <int EPI>
__global__ void __launch_bounds__(256) gemm_k(const __hip_bfloat16* __restrict__ A,
                                              const __hip_bfloat16* __restrict__ BT,
                                              __hip_bfloat16* __restrict__ Cb,
                                              float* __restrict__ Co,
                                              const float* __restrict__ X,
                                              int M, int N, int K) {
  __shared__ __hip_bfloat16 lA[BM * BK];  // 8 KB
  __shared__ __hip_bfloat16 lB[BN * BK];  // 8 KB

  // bijective XCD swizzle (grid divisible by 8): contiguous wg chunk per XCD
  int nwg = gridDim.x;
  int bid = blockIdx.x;
  int cpx = nwg >> 3;
  int wg = (bid & 7) * cpx + (bid >> 3);

  int nt = N / BN;
  int m0 = (wg / nt) * BM;
  int n0 = (wg % nt) * BN;

  int tid = threadIdx.x;
  int lane = tid & 63;
  int w = tid >> 6;                 // wave id 0..3
  int wm = (w >> 1) << 6;           // wave's 64-row offset
  int wn = (w & 1) << 6;            // wave's 64-col offset
  int r16 = lane & 15;
  int k8 = (lane >> 4) << 3;        // k-offset within 32: {0,8,16,24}

  // staging geometry: 8 chunks of 512 elems; wave w owns chunks w and w+4
  int colA = (lane & 3) * 8;        // 0,8,16,24
  int rsub = lane >> 2;             // 0..15
  int row0 = w * 16 + rsub;         // chunk w
  int row1 = (4 + w) * 16 + rsub;   // chunk w+4

  f32x4 acc[4][4] = {};

  for (int k0 = 0; k0 < K; k0 += BK) {
    gl_lds16(&A[(size_t)(m0 + row0) * K + k0 + colA], &lA[(size_t)w * 512]);
    gl_lds16(&A[(size_t)(m0 + row1) * K + k0 + colA], &lA[(size_t)(4 + w) * 512]);
    gl_lds16(&BT[(size_t)(n0 + row0) * K + k0 + colA], &lB[(size_t)w * 512]);
    gl_lds16(&BT[(size_t)(n0 + row1) * K + k0 + colA], &lB[(size_t)(4 + w) * 512]);
    asm volatile("s_waitcnt vmcnt(0)" ::: "memory");
    __syncthreads();

    bf16x8 af[4], bfr[4];
#pragma unroll
    for (int i = 0; i < 4; ++i)
      af[i] = *(const bf16x8*)&lA[(wm + 16 * i + r16) * BK + k8];
#pragma unroll
    for (int j = 0; j < 4; ++j)
      bfr[j] = *(const bf16x8*)&lB[(wn + 16 * j + r16) * BK + k8];
#pragma unroll
    for (int i = 0; i < 4; ++i)
#pragma unroll
      for (int j = 0; j < 4; ++j)
        acc[i][j] = __builtin_amdgcn_mfma_f32_16x16x32_bf16(af[i], bfr[j], acc[i][j], 0, 0, 0);
    __syncthreads();
  }

  // epilogue: D row = (lane>>4)*4 + r, col = lane&15  (m89-verified layout)
#pragma unroll
  for (int i = 0; i < 4; ++i) {
    int grow_base = m0 + wm + 16 * i + ((lane >> 4) << 2);
#pragma unroll
    for (int j = 0; j < 4; ++j) {
      int gcol = n0 + wn + 16 * j + (lane & 15);
#pragma unroll
      for (int r = 0; r < 4; ++r) {
        int grow = grow_base + r;
        float v = acc[i][j][r];
        if constexpr (EPI == 1) {
          // v0 index j0 = p*512 + n -> dst col = 4*(j0%256) + j0/256 = 4*(n&255) + 2p + (n>>8)
          int b = grow >> 1, p = grow & 1;
          Cb[(size_t)b * 1024 + 4 * (gcol & 255) + (p << 1) + (gcol >> 8)] = __float2bfloat16(v);
        } else if constexpr (EPI == 2) {
          // h2 flat j0 = g*256 + n -> dst col = 4*n + g
          int b = grow >> 2, g = grow & 3;
          Cb[(size_t)b * 1024 + 4 * gcol + g] = __float2bfloat16(v);
        } else if constexpr (EPI == 3) {
          Cb[(size_t)grow * N + gcol] = __float2bfloat16(fmaxf(v, 0.f));
        } else {
          float xv = X[(size_t)grow * N + gcol];
          Co[(size_t)grow * N + gcol] = xv / (1.f + __expf(-v));
        }
      }
    }
  }
}

// ---------- launch ----------
extern "C" void kernel_launch(void* const* d_in, const int* in_sizes, int n_in,
                              void* d_out, int out_size, void* d_ws, size_t ws_size,
                              hipStream_t stream) {
  const float* x  = (const float*)d_in[0];
  const float* W1 = (const float*)d_in[1];
  const float* W2 = (const float*)d_in[2];
  const float* W3 = (const float*)d_in[3];
  const float* W4 = (const float*)d_in[4];

  const int B = 131072;

  char* ws = (char*)d_ws;
  __hip_bfloat16* W1T = (__hip_bfloat16*)(ws);                 // 512x512  (N,K) = 512 KB
  __hip_bfloat16* W2T = (__hip_bfloat16*)(ws + 524288);        // 256x256  = 128 KB
  __hip_bfloat16* W3T = (__hip_bfloat16*)(ws + 655360);        // 256x256  = 128 KB
  __hip_bfloat16* W4T = (__hip_bfloat16*)(ws + 786432);        // 512x1024 = 1 MB
  __hip_bfloat16* bufA = (__hip_bfloat16*)(ws + 2097152);      // 256 MB  (h0 / v3)
  __hip_bfloat16* bufB = bufA + (size_t)134217728;             // 256 MB  (v1 / h3)

  // weight prep (bf16 + transpose to (N,K))
  wtrans_kernel<<<(512 * 512) / 256, 256, 0, stream>>>(W1, W1T, 512, 512);
  wtrans_kernel<<<(256 * 256) / 256, 256, 0, stream>>>(W2, W2T, 256, 256);
  wtrans_kernel<<<(256 * 256) / 256, 256, 0, stream>>>(W3, W3T, 256, 256);
  wtrans_kernel<<<(1024 * 512) / 256, 256, 0, stream>>>(W4, W4T, 1024, 512);

  // sort: h0 = [x; sorted(x)] as (2B, 512) bf16 into bufA
  sort_kernel<<<B, 256, 0, stream>>>(x, bufA);

  // G1: (2B,512)@(512,512) -> perm-scatter -> v1 (B,1024) in bufB
  gemm_k<1><<<(2 * B / BM) * (512 / BN), 256, 0, stream>>>(bufA, W1T, bufB, nullptr, nullptr,
                                                           2 * B, 512, 512);
  // G2: (4B,256)@(256,256) -> perm-scatter -> v3 (B,1024) in bufA
  gemm_k<2><<<(4 * B / BM) * (256 / BN), 256, 0, stream>>>(bufB, W2T, bufA, nullptr, nullptr,
                                                           4 * B, 256, 256);
  // G3: (4B,256)@(256,256) + relu -> h3 (B,1024) in bufB
  gemm_k<3><<<(4 * B / BM) * (256 / BN), 256, 0, stream>>>(bufA, W3T, bufB, nullptr, nullptr,
                                                           4 * B, 256, 256);
  // G4: (B,1024)@(1024,512) + sigmoid * x -> out f32
  gemm_k<4><<<(B / BM) * (512 / BN), 256, 0, stream>>>(bufB, W4T, nullptr, (float*)d_out, x,
                                                       B, 512, 1024);
}

// Round 2
// 1145.328 us; speedup vs baseline: 1.2082x; 1.2082x over previous
//
#include <hip/hip_runtime.h>
#include <hip/hip_bf16.h>
#include <cstdint>
#include <cstddef>

// ---------- types ----------
typedef short bf16x8 __attribute__((ext_vector_type(8)));   // 8 bf16 in 4 VGPRs
typedef float f32x4 __attribute__((ext_vector_type(4)));

#define BM 128
#define BN 128
#define BK 32

// async global->LDS, 16B per lane. LDS dest is wave-uniform base + lane*16.
__device__ __forceinline__ void gl_lds16(const __hip_bfloat16* gp, __hip_bfloat16* lp) {
  __builtin_amdgcn_global_load_lds((const __attribute__((address_space(1))) void*)gp,
                                   (__attribute__((address_space(3))) void*)lp, 16, 0, 0);
}

// ---------- weight transpose + bf16 convert: dst[c*R + r] = src[r*C + c] ----------
__global__ void __launch_bounds__(256) wtrans_kernel(const float* __restrict__ src,
                                                     __hip_bfloat16* __restrict__ dst,
                                                     int R, int C) {
  int idx = blockIdx.x * 256 + threadIdx.x;
  if (idx >= R * C) return;
  int r = idx / C, c = idx % C;
  dst[(size_t)c * R + r] = __float2bfloat16(src[idx]);
}

// ---------- per-row sort: one WAVE per row, fully in-register bitonic ----------
// element index e = lane*8 + r  (r = register 0..7)
// j < 8  : in-register compare-exchange (no cross-lane traffic)
// j >= 8 : __shfl_xor with lane mask j/8
__global__ void __launch_bounds__(256) sort_kernel(const float* __restrict__ x,
                                                   __hip_bfloat16* __restrict__ h0) {
  int row = blockIdx.x * 4 + (threadIdx.x >> 6);   // wave id = batch row
  int lane = threadIdx.x & 63;
  const float* xr = x + (size_t)row * 512;

  float v[8];
  *(float4*)&v[0] = *(const float4*)&xr[lane * 8];
  *(float4*)&v[4] = *(const float4*)&xr[lane * 8 + 4];

  // emit unsorted half: h0[row][0..512) = x (bf16), 16B per lane
  __hip_bfloat16* h = h0 + (size_t)row * 1024;
  {
    alignas(16) __hip_bfloat16 ob[8];
#pragma unroll
    for (int i = 0; i < 8; ++i) ob[i] = __float2bfloat16(v[i]);
    *(bf16x8*)&h[lane * 8] = *(const bf16x8*)ob;
  }

  // bitonic sort ascending over e = lane*8 + r
#pragma unroll
  for (int k = 2; k <= 512; k <<= 1) {
#pragma unroll
    for (int j = k >> 1; j > 0; j >>= 1) {
      if (j >= 8) {
        int L = j >> 3;
        bool lower = (lane & L) == 0;
        bool up = (((lane * 8) & k) == 0);
        bool sel = (lower == up);
#pragma unroll
        for (int r = 0; r < 8; ++r) {
          float pv = __shfl_xor(v[r], L, 64);
          float mn = fminf(v[r], pv), mx = fmaxf(v[r], pv);
          v[r] = sel ? mn : mx;
        }
      } else {
#pragma unroll
        for (int r = 0; r < 8; ++r) {
          if ((r & j) == 0) {
            int r2 = r | j;
            bool up = ((((lane * 8) + r) & k) == 0);
            float a = v[r], b = v[r2];
            float mn = fminf(a, b), mx = fmaxf(a, b);
            v[r] = up ? mn : mx;
            v[r2] = up ? mx : mn;
          }
        }
      }
    }
  }

  // emit sorted half: h0[row][512..1024)
  {
    alignas(16) __hip_bfloat16 ob[8];
#pragma unroll
    for (int i = 0; i < 8; ++i) ob[i] = __float2bfloat16(v[i]);
    *(bf16x8*)&h[512 + lane * 8] = *(const bf16x8*)ob;
  }
}

// ---------- GEMM: C(M,N) = A(M,K) @ BT(N,K)^T, bf16 in, f32 accum ----------
// EPI: 1 = perm-scatter after GEMM1 (rows=2b+p, N=512)
//      2 = perm-scatter after G2   (rows=4b+g, N=256)
//      3 = relu, plain bf16 store
//      4 = sigmoid(acc) * x, f32 store
template <int EPI>
__global__ void __launch_bounds__(256) gemm_k(const __hip_bfloat16* __restrict__ A,
                                              const __hip_bfloat16* __restrict__ BT,
                                              __hip_bfloat16* __restrict__ Cb,
                                              float* __restrict__ Co,
                                              const float* __restrict__ X,
                                              int M, int N, int K) {
  __shared__ __hip_bfloat16 lA[BM * BK];  // 8 KB
  __shared__ __hip_bfloat16 lB[BN * BK];  // 8 KB

  // bijective XCD swizzle (grid divisible by 8): contiguous wg chunk per XCD
  int nwg = gridDim.x;
  int bid = blockIdx.x;
  int cpx = nwg >> 3;
  int wg = (bid & 7) * cpx + (bid >> 3);

  int nt = N / BN;
  int m0 = (wg / nt) * BM;
  int n0 = (wg % nt) * BN;

  int tid = threadIdx.x;
  int lane = tid & 63;
  int w = tid >> 6;                 // wave id 0..3
  int wm = (w >> 1) << 6;           // wave's 64-row offset
  int wn = (w & 1) << 6;            // wave's 64-col offset
  int r16 = lane & 15;
  int k8 = (lane >> 4) << 3;        // k-offset within 32: {0,8,16,24}

  // staging geometry: 8 chunks of 512 elems; wave w owns chunks w and w+4
  int colA = (lane & 3) * 8;        // 0,8,16,24
  int rsub = lane >> 2;             // 0..15
  int row0 = w * 16 + rsub;         // chunk w
  int row1 = (4 + w) * 16 + rsub;   // chunk w+4

  f32x4 acc[4][4] = {};

  for (int k0 = 0; k0 < K; k0 += BK) {
    gl_lds16(&A[(size_t)(m0 + row0) * K + k0 + colA], &lA[(size_t)w * 512]);
    gl_lds16(&A[(size_t)(m0 + row1) * K + k0 + colA], &lA[(size_t)(4 + w) * 512]);
    gl_lds16(&BT[(size_t)(n0 + row0) * K + k0 + colA], &lB[(size_t)w * 512]);
    gl_lds16(&BT[(size_t)(n0 + row1) * K + k0 + colA], &lB[(size_t)(4 + w) * 512]);
    asm volatile("s_waitcnt vmcnt(0)" ::: "memory");
    __syncthreads();

    bf16x8 af[4], bfr[4];
#pragma unroll
    for (int i = 0; i < 4; ++i)
      af[i] = *(const bf16x8*)&lA[(wm + 16 * i + r16) * BK + k8];
#pragma unroll
    for (int j = 0; j < 4; ++j)
      bfr[j] = *(const bf16x8*)&lB[(wn + 16 * j + r16) * BK + k8];
#pragma unroll
    for (int i = 0; i < 4; ++i)
#pragma unroll
      for (int j = 0; j < 4; ++j)
        acc[i][j] = __builtin_amdgcn_mfma_f32_16x16x32_bf16(af[i], bfr[j], acc[i][j], 0, 0, 0);
    __syncthreads();
  }

  // epilogue: D row = (lane>>4)*4 + r, col = lane&15  (m89-verified layout)
#pragma unroll
  for (int i = 0; i < 4; ++i) {
    int grow_base = m0 + wm + 16 * i + ((lane >> 4) << 2);
#pragma unroll
    for (int j = 0; j < 4; ++j) {
      int gcol = n0 + wn + 16 * j + (lane & 15);
#pragma unroll
      for (int r = 0; r < 4; ++r) {
        int grow = grow_base + r;
        float v = acc[i][j][r];
        if constexpr (EPI == 1) {
          // v0 index j0 = p*512 + n -> dst col = 4*(n&255) + 2p + (n>>8)
          int b = grow >> 1, p = grow & 1;
          Cb[(size_t)b * 1024 + 4 * (gcol & 255) + (p << 1) + (gcol >> 8)] = __float2bfloat16(v);
        } else if constexpr (EPI == 2) {
          // h2 flat j0 = g*256 + n -> dst col = 4*n + g
          int b = grow >> 2, g = grow & 3;
          Cb[(size_t)b * 1024 + 4 * gcol + g] = __float2bfloat16(v);
        } else if constexpr (EPI == 3) {
          Cb[(size_t)grow * N + gcol] = __float2bfloat16(fmaxf(v, 0.f));
        } else {
          float xv = X[(size_t)grow * N + gcol];
          Co[(size_t)grow * N + gcol] = xv / (1.f + __expf(-v));
        }
      }
    }
  }
}

// ---------- launch ----------
extern "C" void kernel_launch(void* const* d_in, const int* in_sizes, int n_in,
                              void* d_out, int out_size, void* d_ws, size_t ws_size,
                              hipStream_t stream) {
  const float* x  = (const float*)d_in[0];
  const float* W1 = (const float*)d_in[1];
  const float* W2 = (const float*)d_in[2];
  const float* W3 = (const float*)d_in[3];
  const float* W4 = (const float*)d_in[4];

  const int B = 131072;

  char* ws = (char*)d_ws;
  __hip_bfloat16* W1T = (__hip_bfloat16*)(ws);                 // 512x512  (N,K) = 512 KB
  __hip_bfloat16* W2T = (__hip_bfloat16*)(ws + 524288);        // 256x256  = 128 KB
  __hip_bfloat16* W3T = (__hip_bfloat16*)(ws + 655360);        // 256x256  = 128 KB
  __hip_bfloat16* W4T = (__hip_bfloat16*)(ws + 786432);        // 512x1024 = 1 MB
  __hip_bfloat16* bufA = (__hip_bfloat16*)(ws + 2097152);      // 256 MB  (h0 / v3)
  __hip_bfloat16* bufB = bufA + (size_t)134217728;             // 256 MB  (v1 / h3)

  // weight prep (bf16 + transpose to (N,K))
  wtrans_kernel<<<(512 * 512) / 256, 256, 0, stream>>>(W1, W1T, 512, 512);
  wtrans_kernel<<<(256 * 256) / 256, 256, 0, stream>>>(W2, W2T, 256, 256);
  wtrans_kernel<<<(256 * 256) / 256, 256, 0, stream>>>(W3, W3T, 256, 256);
  wtrans_kernel<<<(1024 * 512) / 256, 256, 0, stream>>>(W4, W4T, 1024, 512);

  // sort: h0 = [x; sorted(x)] as (2B, 512) bf16 into bufA  (1 wave per row)
  sort_kernel<<<B / 4, 256, 0, stream>>>(x, bufA);

  // G1: (2B,512)@(512,512) -> perm-scatter -> v1 (B,1024) in bufB
  gemm_k<1><<<(2 * B / BM) * (512 / BN), 256, 0, stream>>>(bufA, W1T, bufB, nullptr, nullptr,
                                                           2 * B, 512, 512);
  // G2: (4B,256)@(256,256) -> perm-scatter -> v3 (B,1024) in bufA
  gemm_k<2><<<(4 * B / BM) * (256 / BN), 256, 0, stream>>>(bufB, W2T, bufA, nullptr, nullptr,
                                                           4 * B, 256, 256);
  // G3: (4B,256)@(256,256) + relu -> h3 (B,1024) in bufB
  gemm_k<3><<<(4 * B / BM) * (256 / BN), 256, 0, stream>>>(bufA, W3T, bufB, nullptr, nullptr,
                                                           4 * B, 256, 256);
  // G4: (B,1024)@(1024,512) + sigmoid * x -> out f32
  gemm_k<4><<<(B / BM) * (512 / BN), 256, 0, stream>>>(bufB, W4T, nullptr, (float*)d_out, x,
                                                       B, 512, 1024);
}

// Round 3
// 1118.630 us; speedup vs baseline: 1.2371x; 1.0239x over previous
//
#include <hip/hip_runtime.h>
#include <hip/hip_bf16.h>
#include <cstdint>
#include <cstddef>

// ---------- types ----------
typedef short bf16x8 __attribute__((ext_vector_type(8)));   // 8 bf16 in 4 VGPRs
typedef float f32x4 __attribute__((ext_vector_type(4)));

#define BM 128
#define BN 128
#define BK 32
#define NBUF 3

// async global->LDS, 16B per lane. LDS dest is wave-uniform base + lane*16.
__device__ __forceinline__ void gl_lds16(const __hip_bfloat16* gp, __hip_bfloat16* lp) {
  __builtin_amdgcn_global_load_lds((const __attribute__((address_space(1))) void*)gp,
                                   (__attribute__((address_space(3))) void*)lp, 16, 0, 0);
}

// ---------- weight transpose + bf16 convert: dst[c*R + r] = src[r*C + c] ----------
__global__ void __launch_bounds__(256) wtrans_kernel(const float* __restrict__ src,
                                                     __hip_bfloat16* __restrict__ dst,
                                                     int R, int C) {
  int idx = blockIdx.x * 256 + threadIdx.x;
  if (idx >= R * C) return;
  int r = idx / C, c = idx % C;
  dst[(size_t)c * R + r] = __float2bfloat16(src[idx]);
}

// ---------- per-row sort: one WAVE per row, fully in-register bitonic ----------
__global__ void __launch_bounds__(256) sort_kernel(const float* __restrict__ x,
                                                   __hip_bfloat16* __restrict__ h0) {
  int row = blockIdx.x * 4 + (threadIdx.x >> 6);   // wave id = batch row
  int lane = threadIdx.x & 63;
  const float* xr = x + (size_t)row * 512;

  float v[8];
  *(float4*)&v[0] = *(const float4*)&xr[lane * 8];
  *(float4*)&v[4] = *(const float4*)&xr[lane * 8 + 4];

  __hip_bfloat16* h = h0 + (size_t)row * 1024;
  {
    alignas(16) __hip_bfloat16 ob[8];
#pragma unroll
    for (int i = 0; i < 8; ++i) ob[i] = __float2bfloat16(v[i]);
    *(bf16x8*)&h[lane * 8] = *(const bf16x8*)ob;
  }

#pragma unroll
  for (int k = 2; k <= 512; k <<= 1) {
#pragma unroll
    for (int j = k >> 1; j > 0; j >>= 1) {
      if (j >= 8) {
        int L = j >> 3;
        bool lower = (lane & L) == 0;
        bool up = (((lane * 8) & k) == 0);
        bool sel = (lower == up);
#pragma unroll
        for (int r = 0; r < 8; ++r) {
          float pv = __shfl_xor(v[r], L, 64);
          float mn = fminf(v[r], pv), mx = fmaxf(v[r], pv);
          v[r] = sel ? mn : mx;
        }
      } else {
#pragma unroll
        for (int r = 0; r < 8; ++r) {
          if ((r & j) == 0) {
            int r2 = r | j;
            bool up = ((((lane * 8) + r) & k) == 0);
            float a = v[r], b = v[r2];
            float mn = fminf(a, b), mx = fmaxf(a, b);
            v[r] = up ? mn : mx;
            v[r2] = up ? mx : mn;
          }
        }
      }
    }
  }

  {
    alignas(16) __hip_bfloat16 ob[8];
#pragma unroll
    for (int i = 0; i < 8; ++i) ob[i] = __float2bfloat16(v[i]);
    *(bf16x8*)&h[512 + lane * 8] = *(const bf16x8*)ob;
  }
}

// ---------- GEMM: C(M,N) = A(M,K) @ BT(N,K)^T, bf16 in, f32 accum ----------
// Depth-2 counted-vmcnt pipeline: 3 LDS buffers, STAGE(t+2) issued before
// compute(t), s_waitcnt vmcnt(4) (next tile's 4 loads stay in flight across
// the raw s_barrier). No __syncthreads in the K-loop (avoids compiler's
// vmcnt(0) drain).
// EPI: 1 = perm-scatter after G1 (rows=2b+p, N=512)
//      2 = perm-scatter after G2 (rows=4b+g, N=256)
//      3 = relu, plain bf16 store
//      4 = sigmoid(acc) * x, f32 store
template <int EPI>
__global__ void __launch_bounds__(256) gemm_k(const __hip_bfloat16* __restrict__ A,
                                              const __hip_bfloat16* __restrict__ BT,
                                              __hip_bfloat16* __restrict__ Cb,
                                              float* __restrict__ Co,
                                              const float* __restrict__ X,
                                              int M, int N, int K) {
  __shared__ __hip_bfloat16 lA[NBUF][BM * BK];  // 3 x 8 KB
  __shared__ __hip_bfloat16 lB[NBUF][BN * BK];  // 3 x 8 KB

  // bijective XCD swizzle (grid divisible by 8)
  int nwg = gridDim.x;
  int bid = blockIdx.x;
  int cpx = nwg >> 3;
  int wg = (bid & 7) * cpx + (bid >> 3);

  int nt_tiles = N / BN;
  int m0 = (wg / nt_tiles) * BM;
  int n0 = (wg % nt_tiles) * BN;

  int tid = threadIdx.x;
  int lane = tid & 63;
  int w = tid >> 6;                 // wave id 0..3
  int wm = (w >> 1) << 6;           // wave's 64-row offset
  int wn = (w & 1) << 6;            // wave's 64-col offset
  int r16 = lane & 15;
  int k8 = (lane >> 4) << 3;        // k-offset within 32: {0,8,16,24}

  // staging geometry: 8 chunks of 512 elems; wave w owns chunks w and w+4
  int colA = (lane & 3) * 8;        // 0,8,16,24
  int rsub = lane >> 2;             // 0..15
  int row0 = w * 16 + rsub;         // chunk w
  int row1 = (4 + w) * 16 + rsub;   // chunk w+4

  f32x4 acc[4][4] = {};

#define STAGE(t, buf)                                                          \
  do {                                                                         \
    int k0_ = (t) * BK;                                                        \
    gl_lds16(&A[(size_t)(m0 + row0) * K + k0_ + colA], &lA[buf][w * 512]);     \
    gl_lds16(&A[(size_t)(m0 + row1) * K + k0_ + colA], &lA[buf][(4 + w) * 512]); \
    gl_lds16(&BT[(size_t)(n0 + row0) * K + k0_ + colA], &lB[buf][w * 512]);    \
    gl_lds16(&BT[(size_t)(n0 + row1) * K + k0_ + colA], &lB[buf][(4 + w) * 512]); \
  } while (0)

  int nt = K / BK;  // >= 8 for all our shapes
  STAGE(0, 0);
  STAGE(1, 1);
  asm volatile("s_waitcnt vmcnt(4)" ::: "memory");  // tile 0 landed; tile 1 in flight
  __builtin_amdgcn_s_barrier();

  int cur = 0;
  for (int t = 0; t < nt; ++t) {
    int nb = cur + 2; if (nb >= NBUF) nb -= NBUF;
    if (t + 2 < nt) STAGE(t + 2, nb);

    bf16x8 af[4], bfr[4];
#pragma unroll
    for (int i = 0; i < 4; ++i)
      af[i] = *(const bf16x8*)&lA[cur][(wm + 16 * i + r16) * BK + k8];
#pragma unroll
    for (int j = 0; j < 4; ++j)
      bfr[j] = *(const bf16x8*)&lB[cur][(wn + 16 * j + r16) * BK + k8];
#pragma unroll
    for (int i = 0; i < 4; ++i)
#pragma unroll
      for (int j = 0; j < 4; ++j)
        acc[i][j] = __builtin_amdgcn_mfma_f32_16x16x32_bf16(af[i], bfr[j], acc[i][j], 0, 0, 0);

    if (t + 2 < nt) {
      asm volatile("s_waitcnt vmcnt(4)" ::: "memory");   // next tile landed, newest stays in flight
    } else if (t + 1 < nt) {
      asm volatile("s_waitcnt vmcnt(0)" ::: "memory");   // drain for final tile
    }
    if (t + 1 < nt) __builtin_amdgcn_s_barrier();
    cur = (cur + 1 == NBUF) ? 0 : cur + 1;
  }
#undef STAGE

  // epilogue: D row = (lane>>4)*4 + r, col = lane&15  (m89-verified layout)
#pragma unroll
  for (int i = 0; i < 4; ++i) {
    int grow_base = m0 + wm + 16 * i + ((lane >> 4) << 2);
#pragma unroll
    for (int j = 0; j < 4; ++j) {
      int gcol = n0 + wn + 16 * j + (lane & 15);
#pragma unroll
      for (int r = 0; r < 4; ++r) {
        int grow = grow_base + r;
        float v = acc[i][j][r];
        if constexpr (EPI == 1) {
          // v0 index j0 = p*512 + n -> dst col = 4*(n&255) + 2p + (n>>8)
          int b = grow >> 1, p = grow & 1;
          Cb[(size_t)b * 1024 + 4 * (gcol & 255) + (p << 1) + (gcol >> 8)] = __float2bfloat16(v);
        } else if constexpr (EPI == 2) {
          // h2 flat j0 = g*256 + n -> dst col = 4*n + g
          int b = grow >> 2, g = grow & 3;
          Cb[(size_t)b * 1024 + 4 * gcol + g] = __float2bfloat16(v);
        } else if constexpr (EPI == 3) {
          Cb[(size_t)grow * N + gcol] = __float2bfloat16(fmaxf(v, 0.f));
        } else {
          float xv = X[(size_t)grow * N + gcol];
          Co[(size_t)grow * N + gcol] = xv / (1.f + __expf(-v));
        }
      }
    }
  }
}

// ---------- launch ----------
extern "C" void kernel_launch(void* const* d_in, const int* in_sizes, int n_in,
                              void* d_out, int out_size, void* d_ws, size_t ws_size,
                              hipStream_t stream) {
  const float* x  = (const float*)d_in[0];
  const float* W1 = (const float*)d_in[1];
  const float* W2 = (const float*)d_in[2];
  const float* W3 = (const float*)d_in[3];
  const float* W4 = (const float*)d_in[4];

  const int B = 131072;

  char* ws = (char*)d_ws;
  __hip_bfloat16* W1T = (__hip_bfloat16*)(ws);                 // 512x512  (N,K) = 512 KB
  __hip_bfloat16* W2T = (__hip_bfloat16*)(ws + 524288);        // 256x256  = 128 KB
  __hip_bfloat16* W3T = (__hip_bfloat16*)(ws + 655360);        // 256x256  = 128 KB
  __hip_bfloat16* W4T = (__hip_bfloat16*)(ws + 786432);        // 512x1024 = 1 MB
  __hip_bfloat16* bufA = (__hip_bfloat16*)(ws + 2097152);      // 256 MB  (h0 / v3)
  __hip_bfloat16* bufB = bufA + (size_t)134217728;             // 256 MB  (v1 / h3)

  // weight prep (bf16 + transpose to (N,K))
  wtrans_kernel<<<(512 * 512) / 256, 256, 0, stream>>>(W1, W1T, 512, 512);
  wtrans_kernel<<<(256 * 256) / 256, 256, 0, stream>>>(W2, W2T, 256, 256);
  wtrans_kernel<<<(256 * 256) / 256, 256, 0, stream>>>(W3, W3T, 256, 256);
  wtrans_kernel<<<(1024 * 512) / 256, 256, 0, stream>>>(W4, W4T, 1024, 512);

  // sort: h0 = [x; sorted(x)] as (2B, 512) bf16 into bufA  (1 wave per row)
  sort_kernel<<<B / 4, 256, 0, stream>>>(x, bufA);

  // G1: (2B,512)@(512,512) -> perm-scatter -> v1 (B,1024) in bufB
  gemm_k<1><<<(2 * B / BM) * (512 / BN), 256, 0, stream>>>(bufA, W1T, bufB, nullptr, nullptr,
                                                           2 * B, 512, 512);
  // G2: (4B,256)@(256,256) -> perm-scatter -> v3 (B,1024) in bufA
  gemm_k<2><<<(4 * B / BM) * (256 / BN), 256, 0, stream>>>(bufB, W2T, bufA, nullptr, nullptr,
                                                           4 * B, 256, 256);
  // G3: (4B,256)@(256,256) + relu -> h3 (B,1024) in bufB
  gemm_k<3><<<(4 * B / BM) * (256 / BN), 256, 0, stream>>>(bufA, W3T, bufB, nullptr, nullptr,
                                                           4 * B, 256, 256);
  // G4: (B,1024)@(1024,512) + sigmoid * x -> out f32
  gemm_k<4><<<(B / BM) * (512 / BN), 256, 0, stream>>>(bufB, W4T, nullptr, (float*)d_out, x,
                                                       B, 512, 1024);
}